// Round 14
// baseline (140.047 us; speedup 1.0000x reference)
//
#include <hip/hip_runtime.h>

// HONU order-3: out[b] = sum_{i<=j<=k} w[idx(i,j,k)] * xf[b,i]*xf[b,j]*xf[b,k]
// xf = [1, x[b,:]] (127 features). idx closed-form; comb_idx input unused.
//
// R8: MEASUREMENT ROUND #2 (exec vs launch-overhead split). honu6 body is
// repeated 8x IN-KERNEL (asm memory clobber per rep forces re-execution);
// kernel_launch is byte-identical to R7 (same 3 dispatches). So
// dur(R8) - dur(R7) = 7 * E_honu6_exec, independent of launch gaps.
// R6's 12.1 us/launch slope = g + E; R7 (halved DS, zero barriers, global-w)
// matched honu5 exactly, exhausting kernel-side explanations -> suspect g.

#define N_FEAT 127
#define C_TOT  349504        // Te(127)
#define IN_LEN 126
#define NTILES 4
#define NB     192           // blocks per tile; 768 total = 3/CU
#define NTASK  568           // sum_j ceil((j+1)/16)
#define XPAD   132           // x row stride: mult-of-4 (b128 align)
#define NREP   8             // in-kernel repeat (measurement)

typedef float f4 __attribute__((ext_vector_type(4), aligned(4)));

__device__ __forceinline__ int Foff(int i){ const int m = N_FEAT - i; return C_TOT - m*(m+1)*(m+2)/6; }
__device__ __forceinline__ int baseij(int i,int j){ return Foff(i) + (j-i)*N_FEAT - ((i+j-1)*(j-i))/2; }

// task t -> (j, i0): cnt(j) = ceil((j+1)/16); prefix(16a+r) = 8a(a+1) + r(a+1)
__device__ __forceinline__ void decode(int t, int& j, int& i0){
    int a = (int)((sqrtf(1.0f + 0.5f*(float)t) - 1.0f)*0.5f);
    if (a < 0) a = 0;
    while (8*(a+1)*(a+2) <= t) ++a;
    while (a > 0 && 8*a*(a+1) > t) --a;
    const int rem = t - 8*a*(a+1);
    const int ap1 = a + 1;
    int r = 0;
    while ((r+1)*ap1 <= rem) ++r;     // <=15 iters, all scalar
    j  = 16*a + r;
    i0 = (rem - r*ap1) << 4;
}

__global__ __launch_bounds__(256, 4) void honu6(
    const float* __restrict__ x, const float* __restrict__ wp, float* __restrict__ parts)
{
    __shared__ float xS[64*XPAD];     // [64][XPAD]: col0=bias, cols 127..131 = 0
    __shared__ float red[256*4];

    const int tid  = threadIdx.x;
    const int lane = tid & 63;
    const int wv   = tid >> 6;
    const int m    = lane & 15;       // rows m, m+16, m+32, m+48
    const int gq   = lane >> 4;       // streams gq + 4*qq
    const int tile = blockIdx.y;
    const int g    = blockIdx.x;

    #pragma unroll 1
    for (int rep = 0; rep < NREP; ++rep) {
        asm volatile("" ::: "memory");   // force true re-execution each rep

        // ---- stage x tile ----
        const float* xsrc = x + (size_t)tile * 64 * IN_LEN;
        for (int e = tid; e < 64*IN_LEN; e += 256){
            const int r = e / IN_LEN, c = e - r*IN_LEN;
            xS[r*XPAD + c + 1] = xsrc[e];
        }
        if (tid < 64) xS[tid*XPAD] = 1.0f;
        for (int e = tid; e < 64*5; e += 256){          // zero cols 127..131
            const int r = e/5, c = e - r*5;
            xS[r*XPAD + 127 + c] = 0.0f;
        }
        __syncthreads();

        float acc[4] = {0.f, 0.f, 0.f, 0.f};

        // static mirrored task list (same balance as honu5)
        int tl[3];
        tl[0] = g; tl[1] = 383 - g; tl[2] = 384 + g;
        const int ntl = (384 + g < NTASK) ? 3 : 2;

        for (int ti = 0; ti < ntl; ++ti) {
            int j, i0; decode(tl[ti], j, i0);
            const int k0 = j & ~3;
            const int dj = j - k0;                       // 0..3 masked lead elems
            const int Q  = (N_FEAT - k0 + 3) >> 2;       // quads; last hits x pad (=0)

            int voff[4];
            #pragma unroll
            for (int qq = 0; qq < 4; ++qq)
                voff[qq] = baseij(min(i0 + gq + 4*qq, j), j) - dj;

            f4 dd[4];
            #pragma unroll
            for (int qq = 0; qq < 4; ++qq) dd[qq] = (f4){0.f,0.f,0.f,0.f};

            int qstart = wv;
            if (wv == 0 && dj != 0) {
                f4 wq[4], xq[4];
                #pragma unroll
                for (int qq = 0; qq < 4; ++qq) wq[qq] = *(const f4*)(wp + voff[qq]);
                #pragma unroll
                for (int rr = 0; rr < 4; ++rr) xq[rr] = *(const f4*)&xS[(m + 16*rr)*XPAD + k0];
                #pragma unroll
                for (int qq = 0; qq < 4; ++qq) {
                    wq[qq][0] = 0.f;
                    if (dj >= 2) wq[qq][1] = 0.f;
                    if (dj >= 3) wq[qq][2] = 0.f;
                }
                #pragma unroll
                for (int qq = 0; qq < 4; ++qq)
                    #pragma unroll
                    for (int rr = 0; rr < 4; ++rr) {
                        dd[qq][rr] = fmaf(wq[qq][0], xq[rr][0], dd[qq][rr]);
                        dd[qq][rr] = fmaf(wq[qq][1], xq[rr][1], dd[qq][rr]);
                        dd[qq][rr] = fmaf(wq[qq][2], xq[rr][2], dd[qq][rr]);
                        dd[qq][rr] = fmaf(wq[qq][3], xq[rr][3], dd[qq][rr]);
                    }
                qstart = 4;
            }

            #pragma unroll 2
            for (int q = qstart; q < Q; q += 4) {        // waves split quads
                const int kk = k0 + 4*q;
                f4 wq[4], xq[4];
                #pragma unroll
                for (int qq = 0; qq < 4; ++qq) wq[qq] = *(const f4*)(wp + voff[qq] + 4*q);
                #pragma unroll
                for (int rr = 0; rr < 4; ++rr) xq[rr] = *(const f4*)&xS[(m + 16*rr)*XPAD + kk];
                #pragma unroll
                for (int qq = 0; qq < 4; ++qq)
                    #pragma unroll
                    for (int rr = 0; rr < 4; ++rr) {
                        dd[qq][rr] = fmaf(wq[qq][0], xq[rr][0], dd[qq][rr]);
                        dd[qq][rr] = fmaf(wq[qq][1], xq[rr][1], dd[qq][rr]);
                        dd[qq][rr] = fmaf(wq[qq][2], xq[rr][2], dd[qq][rr]);
                        dd[qq][rr] = fmaf(wq[qq][3], xq[rr][3], dd[qq][rr]);
                    }
            }

            const int nI = min(16, j + 1 - i0);
            #pragma unroll
            for (int rr = 0; rr < 4; ++rr) {
                const float* xr = &xS[(m + 16*rr)*XPAD];
                const float xj = xr[j];
                float a = 0.f;
                #pragma unroll
                for (int qq = 0; qq < 4; ++qq) {
                    const int s = gq + 4*qq;
                    const float xi = (s < nI) ? xr[i0 + s] : 0.0f;
                    a = fmaf(xi, dd[qq][rr], a);
                }
                acc[rr] = fmaf(xj, a, acc[rr]);
            }
        }

        // ---- block reduce, plain partial store ----
        *(f4*)&red[tid*4] = (f4){acc[0], acc[1], acc[2], acc[3]};
        __syncthreads();
        if (tid < 64) {
            const int mm = tid & 15, rr = tid >> 4;
            float s = 0.f;
            #pragma unroll
            for (int u = 0; u < 16; ++u) {
                const int src = (u >> 2)*64 + (u & 3)*16 + mm;
                s += red[src*4 + rr];
            }
            parts[((size_t)(tile * NB + g) << 6) + tid] = s;
        }
    }
}

__global__ __launch_bounds__(256) void honu6_reduce(
    const float* __restrict__ parts, float* __restrict__ out)
{
    const int tile = blockIdx.x;
    const int row  = threadIdx.x & 63;
    const int seg  = threadIdx.x >> 6;
    __shared__ float red[256];

    const float* base = parts + ((size_t)tile * NB << 6);
    float s0=0.f, s1=0.f, s2=0.f, s3=0.f;
    for (int g = seg; g < NB; g += 16) {
        s0 += base[(g     ) * 64 + row];
        s1 += base[(g +  4) * 64 + row];
        s2 += base[(g +  8) * 64 + row];
        s3 += base[(g + 12) * 64 + row];
    }
    red[threadIdx.x] = (s0 + s1) + (s2 + s3);
    __syncthreads();
    if (threadIdx.x < 64)
        out[tile * 64 + row] = (red[row] + red[64 + row]) + (red[128 + row] + red[192 + row]);
}

extern "C" void kernel_launch(void* const* d_in, const int* in_sizes, int n_in,
                              void* d_out, int out_size, void* d_ws, size_t ws_size,
                              hipStream_t stream)
{
    const float* x = (const float*)d_in[0];
    const float* w = (const float*)d_in[1];
    // d_in[2] (comb_idx) unused: index table is closed-form.
    float* out   = (float*)d_out;
    float* wpad  = (float*)d_ws;
    float* parts = (float*)d_ws + (1 << 19);

    hipMemcpyAsync(wpad, w, C_TOT * sizeof(float), hipMemcpyDeviceToDevice, stream);

    honu6<<<dim3(NB, NTILES), 256, 0, stream>>>(x, wpad, parts);
    honu6_reduce<<<4, 256, 0, stream>>>(parts, out);
}